// Round 1
// baseline (81.270 us; speedup 1.0000x reference)
//
#include <hip/hip_runtime.h>

constexpr int IMG_H = 128;
constexpr int IMG_W = 128;
constexpr int N_IMG = 4;
constexpr int CXCH = 3;
constexpr int CYCH = 21;
constexpr int RAD = 5;
constexpr int DIA = 11;                    // 2R+1
constexpr int TILE_H = 8;
constexpr int TILE_W = 16;
constexpr int PT_H = TILE_H + 2 * RAD;     // 18
constexpr int PT_W = TILE_W + 2 * RAD;     // 26
constexpr int NPIX = PT_H * PT_W;          // 468
constexpr int NTHREADS = TILE_H * TILE_W;  // 128
constexpr int HW = IMG_H * IMG_W;

// Loss = (1/NHW) * sum_{n,p,delta} kval(p,delta) * (1 - y_p . y_{p+delta})
//   kval = 0.9*exp(-0.5*(xy + 100*|dx|^2)) + 0.1*exp(-0.5*xy)
//   xy (in-bounds)  = ((di)^2 + (dj)^2)/36
//   xy (OOB, zero-pad) = (h^2 + w^2)/36 ; x_off = 0, y_off = 0
// Symmetry: in-bounds pair terms are symmetric -> sum 60 half-window offsets, x2.
// OOB offsets have identical kval per pixel -> n_oob * kval_oob analytic fold.
__global__ __launch_bounds__(NTHREADS)
void gcrf_kernel(const float* __restrict__ x, const float* __restrict__ y,
                 float* __restrict__ out) {
    __shared__ __align__(16) float sy[NPIX * 20];  // y channels 0..19, [pix][20]
    __shared__ __align__(16) float sx[NPIX * 4];   // {x0,x1,x2,y20}    [pix][4]
    __shared__ float s_exy[DIA * DIA];
    __shared__ float s_red[NTHREADS / 64];

    const int tid = threadIdx.x;
    const int n = blockIdx.z;
    const int h0 = blockIdx.y * TILE_H;
    const int w0 = blockIdx.x * TILE_W;

    const float* xb = x + (size_t)n * CXCH * HW;
    const float* yb = y + (size_t)n * CYCH * HW;

    // per-offset xy Gaussian table: exp(-0.5*((di^2+dj^2)/36))
    if (tid < DIA * DIA) {
        int di = tid / DIA - RAD, dj = tid % DIA - RAD;
        s_exy[tid] = __expf(-0.5f * (float)(di * di + dj * dj) * (1.0f / 36.0f));
    }

    // Stage padded tile: zeros outside image (matches zero-pad unfold semantics)
    for (int p = tid; p < NPIX; p += NTHREADS) {
        int ti = p / PT_W, tj = p - ti * PT_W;
        int gh = h0 + ti - RAD, gw = w0 + tj - RAD;
        bool inb = ((unsigned)gh < (unsigned)IMG_H) && ((unsigned)gw < (unsigned)IMG_W);
        int gofs = gh * IMG_W + gw;
        float v[CYCH];
        #pragma unroll
        for (int c = 0; c < CYCH; c++) v[c] = inb ? yb[c * HW + gofs] : 0.0f;
        float xv[CXCH];
        #pragma unroll
        for (int c = 0; c < CXCH; c++) xv[c] = inb ? xb[c * HW + gofs] : 0.0f;
        #pragma unroll
        for (int q = 0; q < 5; q++) {
            *(float4*)&sy[p * 20 + q * 4] =
                make_float4(v[q * 4 + 0], v[q * 4 + 1], v[q * 4 + 2], v[q * 4 + 3]);
        }
        *(float4*)&sx[p * 4] = make_float4(xv[0], xv[1], xv[2], v[20]);
    }
    __syncthreads();

    const int tx = tid & (TILE_W - 1);
    const int ty = tid >> 4;
    const int h = h0 + ty, w = w0 + tx;
    const int cp = (ty + RAD) * PT_W + (tx + RAD);

    const float4 cx4 = *(const float4*)&sx[cp * 4];
    float yc[20];
    #pragma unroll
    for (int q = 0; q < 5; q++) {
        float4 t = *(const float4*)&sy[cp * 20 + q * 4];
        yc[q * 4 + 0] = t.x; yc[q * 4 + 1] = t.y;
        yc[q * 4 + 2] = t.z; yc[q * 4 + 3] = t.w;
    }

    // ---- OOB analytic fold (one-sided, not doubled) ----
    int i0 = max(0, RAD - h), i1 = min(DIA - 1, IMG_H - 1 - h + RAD);
    int j0 = max(0, RAD - w), j1 = min(DIA - 1, IMG_W - 1 - w + RAD);
    int n_oob = DIA * DIA - (i1 - i0 + 1) * (j1 - j0 + 1);
    float acc = 0.0f;
    if (n_oob > 0) {
        float oxy = (float)(h * h + w * w) * (1.0f / 36.0f);
        float s2c = cx4.x * cx4.x + cx4.y * cx4.y + cx4.z * cx4.z;
        float kvo = __expf(-0.5f * oxy) * (0.9f * __expf(-50.0f * s2c) + 0.1f);
        acc = (float)n_oob * kvo;
    }

    // ---- symmetric half-window pair loop (60 offsets), doubled ----
    float accp = 0.0f;
    auto pair_term = [&](int i, int j) {
        int p = cp + (i - RAD) * PT_W + (j - RAD);
        float4 xq = *(const float4*)&sx[p * 4];
        float dot = xq.w * cx4.w;  // y channel 20
        #pragma unroll
        for (int q = 0; q < 5; q++) {
            float4 t = *(const float4*)&sy[p * 20 + q * 4];
            dot += t.x * yc[q * 4 + 0] + t.y * yc[q * 4 + 1] +
                   t.z * yc[q * 4 + 2] + t.w * yc[q * 4 + 3];
        }
        float d0 = xq.x - cx4.x, d1 = xq.y - cx4.y, d2 = xq.z - cx4.z;
        float s2 = d0 * d0 + d1 * d1 + d2 * d2;
        int hh2 = h + (i - RAD);
        int ww2 = w + (j - RAD);
        bool inb = (hh2 < IMG_H) && ((unsigned)ww2 < (unsigned)IMG_W);
        float e1 = inb ? s_exy[i * DIA + j] : 0.0f;  // 0 => OOB handled by fold
        float kv = e1 * (0.9f * __expf(-50.0f * s2) + 0.1f);
        accp += kv * (1.0f - dot);
    };

    #pragma unroll
    for (int j = RAD + 1; j < DIA; j++) pair_term(RAD, j);  // row di=0, dj>0
    for (int i = RAD + 1; i < DIA; i++) {                   // rows di>0
        #pragma unroll
        for (int j = 0; j < DIA; j++) pair_term(i, j);
    }

    float total = acc + 2.0f * accp;

    // block reduce -> one atomic per block
    #pragma unroll
    for (int s = 32; s > 0; s >>= 1) total += __shfl_down(total, s, 64);
    if ((tid & 63) == 0) s_red[tid >> 6] = total;
    __syncthreads();
    if (tid == 0) {
        float bs = 0.0f;
        #pragma unroll
        for (int wv = 0; wv < NTHREADS / 64; wv++) bs += s_red[wv];
        atomicAdd(out, bs * (1.0f / (float)(N_IMG * HW)));
    }
}

extern "C" void kernel_launch(void* const* d_in, const int* in_sizes, int n_in,
                              void* d_out, int out_size, void* d_ws, size_t ws_size,
                              hipStream_t stream) {
    const float* x = (const float*)d_in[0];
    const float* y = (const float*)d_in[1];
    float* out = (float*)d_out;
    hipMemsetAsync(out, 0, sizeof(float), stream);
    dim3 grid(IMG_W / TILE_W, IMG_H / TILE_H, N_IMG);  // (8,16,4) = 512 blocks
    gcrf_kernel<<<grid, NTHREADS, 0, stream>>>(x, y, out);
}

// Round 2
// 76.895 us; speedup vs baseline: 1.0569x; 1.0569x over previous
//
#include <hip/hip_runtime.h>

constexpr int IMG_H = 128;
constexpr int IMG_W = 128;
constexpr int N_IMG = 4;
constexpr int CXCH = 3;
constexpr int CYCH = 21;
constexpr int RAD = 5;
constexpr int DIA = 11;                    // 2R+1
constexpr int TILE_H = 8;
constexpr int TILE_W = 16;
constexpr int PT_H = TILE_H + 2 * RAD;     // 18
constexpr int PT_W = TILE_W + 2 * RAD;     // 26
constexpr int NPIX = PT_H * PT_W;          // 468
constexpr int NPIXT = TILE_H * TILE_W;     // 128 pixels per block
constexpr int NGROUP = 4;                  // offset-split factor
constexpr int NTHREADS = NPIXT * NGROUP;   // 512
constexpr int NPAIR = 60;                  // half-window offsets (doubled)
constexpr int PPG = NPAIR / NGROUP;        // 15 pairs per thread
constexpr int HW = IMG_H * IMG_W;

// Loss = (1/NHW) * sum_{n,p,delta} kval(p,delta) * (1 - y_p . y_{p+delta})
//   kval = 0.9*exp(-0.5*(xy + 100*|dx|^2)) + 0.1*exp(-0.5*xy)
// Symmetry: in-bounds pair terms symmetric -> 60 half-window offsets, x2.
// OOB (zero-pad) offsets have identical kval per pixel -> analytic fold.
// R2: 4-way offset split -> 4 waves/SIMD (was 1) to hide ds_read latency;
//     per-thread chain 60 -> 15 fully unrolled pair terms.
__global__ __launch_bounds__(NTHREADS, 4)
void gcrf_kernel(const float* __restrict__ x, const float* __restrict__ y,
                 float* __restrict__ out) {
    __shared__ __align__(16) float sy[NPIX * 20];  // y ch 0..19, [pix][20]
    __shared__ __align__(16) float sx[NPIX * 4];   // {x0,x1,x2,y20} [pix][4]
    __shared__ int   s_pk[NPAIR];                  // (di<<8) | (dj+8)
    __shared__ float s_e1[NPAIR];                  // exp(-(di^2+dj^2)/72)
    __shared__ float s_red[NTHREADS / 64];

    const int tid = threadIdx.x;
    const int n = blockIdx.z;
    const int h0 = blockIdx.y * TILE_H;
    const int w0 = blockIdx.x * TILE_W;

    const float* xb = x + (size_t)n * CXCH * HW;
    const float* yb = y + (size_t)n * CYCH * HW;

    // pair table: k=0..4 -> (0, 1..5); k=5..59 -> (1+m/11, m%11-5)
    if (tid < NPAIR) {
        int di, dj;
        if (tid < 5) { di = 0; dj = tid + 1; }
        else         { int m = tid - 5; di = 1 + m / 11; dj = m % 11 - 5; }
        s_pk[tid] = (di << 8) | (dj + 8);
        s_e1[tid] = __expf(-0.5f * (float)(di * di + dj * dj) * (1.0f / 36.0f));
    }

    // Stage padded tile: zeros outside image (zero-pad unfold semantics)
    for (int p = tid; p < NPIX; p += NTHREADS) {
        int ti = p / PT_W, tj = p - ti * PT_W;
        int gh = h0 + ti - RAD, gw = w0 + tj - RAD;
        bool inb = ((unsigned)gh < (unsigned)IMG_H) && ((unsigned)gw < (unsigned)IMG_W);
        int gofs = gh * IMG_W + gw;
        float v[CYCH];
        #pragma unroll
        for (int c = 0; c < CYCH; c++) v[c] = inb ? yb[c * HW + gofs] : 0.0f;
        float xv[CXCH];
        #pragma unroll
        for (int c = 0; c < CXCH; c++) xv[c] = inb ? xb[c * HW + gofs] : 0.0f;
        #pragma unroll
        for (int q = 0; q < 5; q++) {
            *(float4*)&sy[p * 20 + q * 4] =
                make_float4(v[q * 4 + 0], v[q * 4 + 1], v[q * 4 + 2], v[q * 4 + 3]);
        }
        *(float4*)&sx[p * 4] = make_float4(xv[0], xv[1], xv[2], v[20]);
    }
    __syncthreads();

    const int g = tid >> 7;          // offset group 0..3 (wave-uniform)
    const int pix = tid & (NPIXT - 1);
    const int tx = pix & (TILE_W - 1);
    const int ty = pix >> 4;
    const int h = h0 + ty, w = w0 + tx;
    const int cp = (ty + RAD) * PT_W + (tx + RAD);

    const float4 cx4 = *(const float4*)&sx[cp * 4];
    float yc[20];
    #pragma unroll
    for (int q = 0; q < 5; q++) {
        float4 t = *(const float4*)&sy[cp * 20 + q * 4];
        yc[q * 4 + 0] = t.x; yc[q * 4 + 1] = t.y;
        yc[q * 4 + 2] = t.z; yc[q * 4 + 3] = t.w;
    }

    // ---- OOB analytic fold (one-sided, not doubled; group 0 only) ----
    float acc = 0.0f;
    if (g == 0) {
        int i0 = max(0, RAD - h), i1 = min(DIA - 1, IMG_H - 1 - h + RAD);
        int j0 = max(0, RAD - w), j1 = min(DIA - 1, IMG_W - 1 - w + RAD);
        int n_oob = DIA * DIA - (i1 - i0 + 1) * (j1 - j0 + 1);
        if (n_oob > 0) {
            float oxy = (float)(h * h + w * w) * (1.0f / 36.0f);
            float s2c = cx4.x * cx4.x + cx4.y * cx4.y + cx4.z * cx4.z;
            float kvo = __expf(-0.5f * oxy) * (0.9f * __expf(-50.0f * s2c) + 0.1f);
            acc = (float)n_oob * kvo;
        }
    }

    // ---- 15 symmetric pair terms for this group's offsets, doubled ----
    float accp = 0.0f;
    #pragma unroll
    for (int t = 0; t < PPG; t++) {
        int k = g * PPG + t;         // wave-uniform -> LDS broadcast reads
        int pk = s_pk[k];
        float e1 = s_e1[k];
        int di = pk >> 8, dj = (pk & 255) - 8;
        int p = cp + di * PT_W + dj;
        float4 xq = *(const float4*)&sx[p * 4];
        float dot = xq.w * cx4.w;    // y channel 20
        #pragma unroll
        for (int q = 0; q < 5; q++) {
            float4 tt = *(const float4*)&sy[p * 20 + q * 4];
            dot += tt.x * yc[q * 4 + 0] + tt.y * yc[q * 4 + 1] +
                   tt.z * yc[q * 4 + 2] + tt.w * yc[q * 4 + 3];
        }
        float d0 = xq.x - cx4.x, d1 = xq.y - cx4.y, d2 = xq.z - cx4.z;
        float s2 = d0 * d0 + d1 * d1 + d2 * d2;
        bool inb = ((h + di) < IMG_H) && ((unsigned)(w + dj) < (unsigned)IMG_W);
        float e = inb ? e1 : 0.0f;   // OOB handled by analytic fold
        float kv = e * (0.9f * __expf(-50.0f * s2) + 0.1f);
        accp += kv * (1.0f - dot);
    }

    float total = acc + 2.0f * accp;

    // block reduce -> one atomic per block
    #pragma unroll
    for (int s = 32; s > 0; s >>= 1) total += __shfl_down(total, s, 64);
    if ((tid & 63) == 0) s_red[tid >> 6] = total;
    __syncthreads();
    if (tid == 0) {
        float bs = 0.0f;
        #pragma unroll
        for (int wv = 0; wv < NTHREADS / 64; wv++) bs += s_red[wv];
        atomicAdd(out, bs * (1.0f / (float)(N_IMG * HW)));
    }
}

extern "C" void kernel_launch(void* const* d_in, const int* in_sizes, int n_in,
                              void* d_out, int out_size, void* d_ws, size_t ws_size,
                              hipStream_t stream) {
    const float* x = (const float*)d_in[0];
    const float* y = (const float*)d_in[1];
    float* out = (float*)d_out;
    hipMemsetAsync(out, 0, sizeof(float), stream);
    dim3 grid(IMG_W / TILE_W, IMG_H / TILE_H, N_IMG);  // (8,16,4) = 512 blocks
    gcrf_kernel<<<grid, NTHREADS, 0, stream>>>(x, y, out);
}